// Round 1
// baseline (969.852 us; speedup 1.0000x reference)
//
#include <hip/hip_runtime.h>
#include <hip/hip_bf16.h>

// Problem constants
#define BB 16
#define N1 256
#define N2 256
#define FA 128
#define FE 128

typedef __attribute__((ext_vector_type(8))) short bf16x8;
typedef __attribute__((ext_vector_type(4))) float f32x4;

static __device__ __forceinline__ unsigned short f2bf(float f) {
    union { float f; unsigned int u; } v; v.f = f;
    unsigned int u = v.u;
    // round-to-nearest-even to bf16
    unsigned int r = (u + 0x7FFFu + ((u >> 16) & 1u)) >> 16;
    return (unsigned short)r;
}

// out[row][g] = x[row,:] @ W[:, g] + bias[g]; 8 rows per block, 128 threads.
// W row-major [128][128] (f-major), reads coalesced over g, L2-resident.
__global__ __launch_bounds__(128) void prep_gemm(const float* __restrict__ x,
                                                 const float* __restrict__ W,
                                                 const float* __restrict__ bias,
                                                 float* __restrict__ out) {
    __shared__ float xs[8][128];
    const int r0 = blockIdx.x * 8;
    const int g = threadIdx.x;
    #pragma unroll
    for (int r = 0; r < 8; ++r)
        xs[r][g] = x[(size_t)(r0 + r) * FA + g];
    __syncthreads();
    float acc[8];
    const float bv = bias[g];
    #pragma unroll
    for (int r = 0; r < 8; ++r) acc[r] = bv;
    for (int f = 0; f < 128; ++f) {
        const float wv = W[f * FA + g];
        #pragma unroll
        for (int r = 0; r < 8; ++r) acc[r] += xs[r][f] * wv;
    }
    #pragma unroll
    for (int r = 0; r < 8; ++r)
        out[(size_t)(r0 + r) * FA + g] = acc[r];
}

// Transpose + convert Mw_e (= M_w[128:,:], [e][g]) into bf16 wT[g][e].
__global__ __launch_bounds__(256) void prep_wt(const float* __restrict__ Mw,
                                               unsigned short* __restrict__ wT) {
    const int idx = blockIdx.x * 256 + threadIdx.x;  // 0..16383
    const int g = idx >> 7, e = idx & 127;
    wT[idx] = f2bf(Mw[(size_t)(FA + e) * FA + g]);
}

#define JT 64     // j rows per LDS tile
#define LDW 136   // padded LDS row stride in bf16 elems (128 + 8, keeps 16B align)

// One block per (b, i). 256 threads = 4 waves; wave w owns j rows [w*16, w*16+16)
// of each 64-row tile. MFMA 16x16x32 bf16, M=j, N=g, K=e.
__global__ __launch_bounds__(256, 2) void edge_main(
    const float* __restrict__ edge,
    const float* __restrict__ valid,
    const float* __restrict__ mx2b,        // ws fp32 [B*N2][FA], includes M_b
    const unsigned short* __restrict__ wT, // ws bf16 [g=128][e=128]
    float* __restrict__ out)               // holds m1 on entry; final result on exit
{
    __shared__ unsigned short wls[128 * LDW];  // 34816 B
    __shared__ unsigned short els[JT * LDW];   // 17408 B
    __shared__ float validS[N2];               // 1024 B
    __shared__ float wmax[4][FA];              // 2048 B

    const int tid = threadIdx.x;
    const int bi = blockIdx.x;      // b*256 + i
    const int b = bi >> 8;
    const int lane = tid & 63;
    const int wv = tid >> 6;

    // ---- stage weight tile (16384 bf16 = 2048 16B chunks, 8/thread) + valid ----
    {
        const uint4* src = (const uint4*)wT;
        #pragma unroll
        for (int k = 0; k < 8; ++k) {
            const int c = k * 256 + tid;   // chunk id
            const int row = c >> 4;        // 16 chunks per 128-elem row
            const int col8 = c & 15;
            const uint4 v = src[c];
            *(uint4*)&wls[row * LDW + col8 * 8] = v;
        }
        validS[tid] = valid[(size_t)bi * N2 + tid];
    }
    __syncthreads();

    // ---- hoist B fragments: wT[g = t*16+n][e = s*32 + q*8 ..+8] ----
    const int n = lane & 15, q = lane >> 4;
    bf16x8 bF[8][4];
    #pragma unroll
    for (int t = 0; t < 8; ++t)
        #pragma unroll
        for (int s = 0; s < 4; ++s)
            bF[t][s] = *(const bf16x8*)&wls[(t * 16 + n) * LDW + s * 32 + q * 8];

    float runmax[8][4];
    #pragma unroll
    for (int t = 0; t < 8; ++t)
        #pragma unroll
        for (int r = 0; r < 4; ++r) runmax[t][r] = -3.0e38f;

    const float* eb = edge + (size_t)bi * (N2 * FE);
    const float* mxb = mx2b + (size_t)b * (N2 * FA);

    for (int it = 0; it < 4; ++it) {
        __syncthreads();  // els reuse barrier
        // ---- stage edge tile: 64 rows x 128 fp32 -> bf16 in LDS ----
        {
            const float4* src = (const float4*)(eb + (size_t)it * (JT * FE));
            #pragma unroll
            for (int k = 0; k < 8; ++k) {
                const int s = k * 256 + tid;  // 0..2047 float4 slots
                const int row = s >> 5;
                const int c4 = s & 31;
                const float4 v = src[s];
                const unsigned short h0 = f2bf(v.x), h1 = f2bf(v.y);
                const unsigned short h2 = f2bf(v.z), h3 = f2bf(v.w);
                uint2 p;
                p.x = (unsigned)h0 | ((unsigned)h1 << 16);
                p.y = (unsigned)h2 | ((unsigned)h3 << 16);
                *(uint2*)&els[row * LDW + c4 * 4] = p;
            }
        }
        __syncthreads();

        // ---- A fragments for this wave's 16-row strip ----
        bf16x8 aF[4];
        #pragma unroll
        for (int s = 0; s < 4; ++s)
            aF[s] = *(const bf16x8*)&els[(wv * 16 + n) * LDW + s * 32 + q * 8];

        #pragma unroll
        for (int t = 0; t < 8; ++t) {
            f32x4 acc = {0.f, 0.f, 0.f, 0.f};
            #pragma unroll
            for (int s = 0; s < 4; ++s)
                acc = __builtin_amdgcn_mfma_f32_16x16x32_bf16(aF[s], bF[t][s], acc, 0, 0, 0);
            const int g = t * 16 + n;
            #pragma unroll
            for (int r = 0; r < 4; ++r) {
                const int jl = it * 64 + wv * 16 + q * 4 + r;  // global j
                const float val = (acc[r] + mxb[(size_t)jl * FA + g]) * validS[jl];
                runmax[t][r] = fmaxf(runmax[t][r], val);
            }
        }
    }

    // ---- reduce over j: regs -> cross-quad shuffle -> cross-wave LDS ----
    {
        float cmax[8];
        #pragma unroll
        for (int t = 0; t < 8; ++t) {
            float m = fmaxf(fmaxf(runmax[t][0], runmax[t][1]),
                            fmaxf(runmax[t][2], runmax[t][3]));
            m = fmaxf(m, __shfl_xor(m, 16, 64));
            m = fmaxf(m, __shfl_xor(m, 32, 64));
            cmax[t] = m;
        }
        if (lane < 16) {
            #pragma unroll
            for (int t = 0; t < 8; ++t) wmax[wv][t * 16 + n] = cmax[t];
        }
    }
    __syncthreads();
    if (tid < FA) {
        const float m2 = fmaxf(fmaxf(wmax[0][tid], wmax[1][tid]),
                               fmaxf(wmax[2][tid], wmax[3][tid]));
        const size_t o = (size_t)bi * FA + tid;
        const float m1 = out[o];  // prep_gemm stored m1 here
        out[o] = fmaxf(m1 + m2, 0.0f);
    }
}

extern "C" void kernel_launch(void* const* d_in, const int* in_sizes, int n_in,
                              void* d_out, int out_size, void* d_ws, size_t ws_size,
                              hipStream_t stream) {
    const float* x1    = (const float*)d_in[0];
    const float* x2    = (const float*)d_in[1];
    const float* edge  = (const float*)d_in[2];
    const float* valid = (const float*)d_in[3];
    const float* W_w   = (const float*)d_in[4];
    const float* W_b   = (const float*)d_in[5];
    const float* M_w   = (const float*)d_in[6];
    const float* M_b   = (const float*)d_in[7];
    float* out = (float*)d_out;

    // ws layout: [0, 32768) wT bf16; [32768, 32768+2MB) mx2b fp32
    unsigned short* wT = (unsigned short*)d_ws;
    float* mx2b = (float*)((char*)d_ws + 32768);

    // m1 = x1 @ W_w + W_b  -> d_out (overwritten by edge_main epilogue)
    prep_gemm<<<BB * N1 / 8, 128, 0, stream>>>(x1, W_w, W_b, out);
    // mx2b = x2 @ M_w[:128] + M_b -> ws
    prep_gemm<<<BB * N2 / 8, 128, 0, stream>>>(x2, M_w, M_b, mx2b);
    // wT = bf16(M_w[128:].T)
    prep_wt<<<64, 256, 0, stream>>>(M_w, wT);
    // fused edge GEMM + masked max + relu(m1 + m2)
    edge_main<<<BB * N1, 256, 0, stream>>>(edge, valid, mx2b, wT, out);
}

// Round 2
// 744.839 us; speedup vs baseline: 1.3021x; 1.3021x over previous
//
#include <hip/hip_runtime.h>
#include <hip/hip_bf16.h>

// Problem constants
#define BB 16
#define N1 256
#define N2 256
#define FA 128
#define FE 128

typedef __attribute__((ext_vector_type(8))) short bf16x8;
typedef __attribute__((ext_vector_type(4))) float f32x4;

static __device__ __forceinline__ unsigned short f2bf(float f) {
    union { float f; unsigned int u; } v; v.f = f;
    unsigned int u = v.u;
    unsigned int r = (u + 0x7FFFu + ((u >> 16) & 1u)) >> 16;  // RNE
    return (unsigned short)r;
}

static __device__ __forceinline__ bf16x8 pack8(float4 lo, float4 hi) {
    bf16x8 r;
    r[0] = (short)f2bf(lo.x); r[1] = (short)f2bf(lo.y);
    r[2] = (short)f2bf(lo.z); r[3] = (short)f2bf(lo.w);
    r[4] = (short)f2bf(hi.x); r[5] = (short)f2bf(hi.y);
    r[6] = (short)f2bf(hi.z); r[7] = (short)f2bf(hi.w);
    return r;
}

// out[row][g] = x[row,:] @ W[:, g] + bias[g]; 8 rows per block, 128 threads.
__global__ __launch_bounds__(128) void prep_gemm(const float* __restrict__ x,
                                                 const float* __restrict__ W,
                                                 const float* __restrict__ bias,
                                                 float* __restrict__ out) {
    __shared__ float xs[8][128];
    const int r0 = blockIdx.x * 8;
    const int g = threadIdx.x;
    #pragma unroll
    for (int r = 0; r < 8; ++r)
        xs[r][g] = x[(size_t)(r0 + r) * FA + g];
    __syncthreads();
    float acc[8];
    const float bv = bias[g];
    #pragma unroll
    for (int r = 0; r < 8; ++r) acc[r] = bv;
    #pragma unroll 8
    for (int f = 0; f < 128; ++f) {
        const float wv = W[f * FA + g];
        #pragma unroll
        for (int r = 0; r < 8; ++r) acc[r] += xs[r][f] * wv;
    }
    #pragma unroll
    for (int r = 0; r < 8; ++r)
        out[(size_t)(r0 + r) * FA + g] = acc[r];
}

// Same GEMM but stores TRANSPOSED: outT[b][g][j] = x2[b,j,:]@W[:,g] + bias[g].
// Thread g owns 8 consecutive j -> two float4 stores per thread.
__global__ __launch_bounds__(128) void prep_gemm_T(const float* __restrict__ x,
                                                   const float* __restrict__ W,
                                                   const float* __restrict__ bias,
                                                   float* __restrict__ outT) {
    __shared__ float xs[8][128];
    const int r0 = blockIdx.x * 8;       // global row (b*256 + j)
    const int b = r0 >> 8;
    const int j0 = r0 & 255;
    const int g = threadIdx.x;
    #pragma unroll
    for (int r = 0; r < 8; ++r)
        xs[r][g] = x[(size_t)(r0 + r) * FA + g];
    __syncthreads();
    float acc[8];
    const float bv = bias[g];
    #pragma unroll
    for (int r = 0; r < 8; ++r) acc[r] = bv;
    #pragma unroll 8
    for (int f = 0; f < 128; ++f) {
        const float wv = W[f * FA + g];
        #pragma unroll
        for (int r = 0; r < 8; ++r) acc[r] += xs[r][f] * wv;
    }
    float4 v0 = {acc[0], acc[1], acc[2], acc[3]};
    float4 v1 = {acc[4], acc[5], acc[6], acc[7]};
    float4* dst = (float4*)&outT[(size_t)(b * 128 + g) * 256 + j0];
    dst[0] = v0;
    dst[1] = v1;
}

// Transpose + convert Mw_e (= M_w[128:,:], [e][g]) into bf16 wT[g][e].
__global__ __launch_bounds__(256) void prep_wt(const float* __restrict__ Mw,
                                               unsigned short* __restrict__ wT) {
    const int idx = blockIdx.x * 256 + threadIdx.x;  // 0..16383
    const int g = idx >> 7, e = idx & 127;
    wT[idx] = f2bf(Mw[(size_t)(FA + e) * FA + g]);
}

// Fused edge GEMM + masked max + relu(m1+m2).
// NO LDS, NO barriers: each wave independently owns one (b,i).
// 1024 blocks x 256 threads (4 waves); wave w of block blk handles bi=blk*4+w.
// Per 16-row j-strip: A-fragments loaded straight from global edge rows
// (contiguous 32B per lane per K-chunk), converted to bf16 in-register.
__global__ __launch_bounds__(256, 2) void edge_main(
    const float* __restrict__ edge,
    const float* __restrict__ valid,
    const float* __restrict__ mx2bT,       // ws fp32 [b][g=128][j=256], includes M_b
    const unsigned short* __restrict__ wT, // ws bf16 [g=128][e=128]
    float* __restrict__ out)               // holds m1 on entry; final result on exit
{
    const int tid = threadIdx.x;
    const int wv = tid >> 6;
    const int lane = tid & 63;
    const int n = lane & 15, q = lane >> 4;
    const int bi = blockIdx.x * 4 + wv;    // 0..4095
    const int b = bi >> 8;

    // ---- hoist B fragments from L2-resident wT: bF[t][s] = wT[t*16+n][s*32+q*8 ..+8]
    bf16x8 bF[8][4];
    #pragma unroll
    for (int t = 0; t < 8; ++t)
        #pragma unroll
        for (int s = 0; s < 4; ++s)
            bF[t][s] = *(const bf16x8*)&wT[(t * 16 + n) * FE + s * 32 + q * 8];

    float runmax[8];
    #pragma unroll
    for (int t = 0; t < 8; ++t) runmax[t] = -3.0e38f;

    const float* eb  = edge + (size_t)bi * (N2 * FE);
    const float* mxT = mx2bT + (size_t)b * (N2 * FA);
    const float* vb  = valid + (size_t)bi * N2;

    for (int strip = 0; strip < 16; ++strip) {
        const int j0 = strip * 16;

        // A: edge row (j0+n), floats [s*32+q*8, +8) -> 8 float4 loads
        const float* erow = eb + (size_t)(j0 + n) * FE + q * 8;
        float4 a[8];
        #pragma unroll
        for (int s = 0; s < 4; ++s) {
            a[2 * s]     = *(const float4*)(erow + s * 32);
            a[2 * s + 1] = *(const float4*)(erow + s * 32 + 4);
        }
        // additive term + mask (L2-resident)
        const float4 vld = *(const float4*)(vb + j0 + q * 4);
        float4 mxv[8];
        #pragma unroll
        for (int t = 0; t < 8; ++t)
            mxv[t] = *(const float4*)(mxT + (size_t)(t * 16 + n) * N2 + j0 + q * 4);

        bf16x8 aF[4];
        #pragma unroll
        for (int s = 0; s < 4; ++s)
            aF[s] = pack8(a[2 * s], a[2 * s + 1]);

        #pragma unroll
        for (int t = 0; t < 8; ++t) {
            f32x4 acc = {0.f, 0.f, 0.f, 0.f};
            #pragma unroll
            for (int s = 0; s < 4; ++s)
                acc = __builtin_amdgcn_mfma_f32_16x16x32_bf16(aF[s], bF[t][s], acc, 0, 0, 0);
            // C layout: col(g-within-tile)=n, row(j-within-strip)=q*4+r
            float v0 = (acc[0] + mxv[t].x) * vld.x;
            float v1 = (acc[1] + mxv[t].y) * vld.y;
            float v2 = (acc[2] + mxv[t].z) * vld.z;
            float v3 = (acc[3] + mxv[t].w) * vld.w;
            runmax[t] = fmaxf(runmax[t], fmaxf(fmaxf(v0, v1), fmaxf(v2, v3)));
        }
    }

    // ---- cross-q reduce (rows q*4+r covered all j with r-fold + this) ----
    #pragma unroll
    for (int t = 0; t < 8; ++t) {
        float m = runmax[t];
        m = fmaxf(m, __shfl_xor(m, 16, 64));
        m = fmaxf(m, __shfl_xor(m, 32, 64));
        runmax[t] = m;
    }
    if (lane < 16) {
        #pragma unroll
        for (int t = 0; t < 8; ++t) {
            const size_t o = (size_t)bi * FA + t * 16 + lane;
            const float m1 = out[o];  // prep_gemm stored m1 here
            out[o] = fmaxf(m1 + runmax[t], 0.0f);
        }
    }
}

extern "C" void kernel_launch(void* const* d_in, const int* in_sizes, int n_in,
                              void* d_out, int out_size, void* d_ws, size_t ws_size,
                              hipStream_t stream) {
    const float* x1    = (const float*)d_in[0];
    const float* x2    = (const float*)d_in[1];
    const float* edge  = (const float*)d_in[2];
    const float* valid = (const float*)d_in[3];
    const float* W_w   = (const float*)d_in[4];
    const float* W_b   = (const float*)d_in[5];
    const float* M_w   = (const float*)d_in[6];
    const float* M_b   = (const float*)d_in[7];
    float* out = (float*)d_out;

    // ws layout: [0, 32768) wT bf16; [32768, 32768 + 2MB) mx2bT fp32
    unsigned short* wT = (unsigned short*)d_ws;
    float* mx2bT = (float*)((char*)d_ws + 32768);

    // m1 = x1 @ W_w + W_b  -> d_out (updated in-place by edge_main epilogue)
    prep_gemm<<<BB * N1 / 8, 128, 0, stream>>>(x1, W_w, W_b, out);
    // mx2bT[b][g][j] = x2 @ M_w[:128] + M_b (transposed store) -> ws
    prep_gemm_T<<<BB * N2 / 8, 128, 0, stream>>>(x2, M_w, M_b, mx2bT);
    // wT = bf16(M_w[128:].T)
    prep_wt<<<64, 256, 0, stream>>>(M_w, wT);
    // fused edge GEMM + masked max + relu(m1 + m2), barrier-free
    edge_main<<<BB * N1 / 4, 256, 0, stream>>>(edge, valid, mx2bT, wT, out);
}